// Round 5
// baseline (1719.461 us; speedup 1.0000x reference)
//
#include <hip/hip_runtime.h>

// Persistent-kernel LSTM: B=128, T=512, D=512, H=512, FORGET_BIAS=1.0
// 128 wgs x 512 thr. wg (mg=wgid&7, hb=wgid>>3): rows 16mg..+16, h-cols
// 32hb..+32, all 4 gates. Wave w: h-col sub-block w*4..w*4+4, ALL 4 gates
// (B-frag col cb = gate*4 + hc). W resident in VGPR/AGPR (32 frags/wave).
//
// R9: tagged-u64 handoff + in-wave gates.
//  * publish = one atomic u64 per bf16-pair: (tag=t+1)<<32 | data. Consumer
//    polls for its exact tag => stale data self-identifies. Removes poison,
//    repoison stores (64MB LLC traffic), the mid-B LBAR, and all periodic
//    vmcnt drains. 2 parity slots suffice: producer can only republish a
//    slot (step t+2, tag t+3) after staging h[t+2], which needs every
//    consumer's h[t+2] publish, which (program order) follows that
//    consumer's completed h[t+1] reads. No ABA.
//  * W repacked so each wave's 16 frag cols = 4 gates x 4 hcols. The 4 gate
//    values of one cell live in 4 lanes of the SAME wave (lane bits [3:2])
//    => 4x shfl_xor register transpose replaces the zbuf LDS round-trip and
//    its wg-wide barrier. Each wave publishes right after its own MFMAs.
//  * hlds double-buffered => exactly ONE lgkm-only barrier per step.
// Fail-fast poll caps kept: protocol failure -> wrong data (passed:false),
// never a hung dispatch.

#define B_ 128
#define T_ 512
#define D_ 512
#define H_ 512
#define POLL_CAP 8192

typedef __bf16 bf16x8 __attribute__((ext_vector_type(8)));
typedef float f32x4 __attribute__((ext_vector_type(4)));
typedef unsigned long long u64;

static __device__ __forceinline__ unsigned short f2bf(float f) {
  return __builtin_bit_cast(unsigned short, (__bf16)f);
}
static __device__ __forceinline__ float fast_sigmoid(float x) {
  return __builtin_amdgcn_rcpf(1.f + __expf(-x));
}
static __device__ __forceinline__ float fast_tanh(float x) {
  float xc = fminf(fmaxf(x, -15.f), 15.f);
  float t = __expf(-2.f * xc);
  return (1.f - t) * __builtin_amdgcn_rcpf(1.f + t);
}

// lgkm-only barrier: does NOT drain vmcnt (publish/out/x-prefetch stores
// stay in flight). asm memory clobbers pin op order on both sides.
#define LBAR()                                             \
  do {                                                     \
    __asm__ volatile("s_waitcnt lgkmcnt(0)" ::: "memory"); \
    __builtin_amdgcn_s_barrier();                          \
    __asm__ volatile("" ::: "memory");                     \
  } while (0)

// ---- pack W [1024][2048] fp32 -> bf16 B-frag layout ----
// frag f = (hb*8 + w)*32 + kt;  Wp[(f*64+lane)*8 + j] = bf16(W[k][col])
//   k = kt*32 + (lane>>4)*8 + j
//   cb = lane&15;  col = (cb>>2)*512 + hb*32 + w*4 + (cb&3)   [R9 mapping]
__global__ __launch_bounds__(256) void pack_w_kernel(const float* __restrict__ W,
                                                     unsigned short* __restrict__ Wp) {
  int tid = blockIdx.x * 256 + threadIdx.x;  // [0, 2^21)
  int j = tid & 7;
  int lane = (tid >> 3) & 63;
  int f = tid >> 9;
  int kt = f & 31;
  int w = (f >> 5) & 7;
  int hb = f >> 8;
  int k = (kt << 5) + ((lane >> 4) << 3) + j;
  int cb = lane & 15;
  int col = ((cb >> 2) << 9) + (hb << 5) + (w << 2) + (cb & 3);
  Wp[tid] = f2bf(W[k * 2048 + col]);
}

// zero hg: 2 slots x 8 groups x 4096 u64 = 512 KB (tag 0 != any t+1 >= 1)
__global__ __launch_bounds__(1024) void init_ws_kernel(unsigned int* __restrict__ hg) {
  hg[blockIdx.x * 1024 + threadIdx.x] = 0u;
}

__global__ __launch_bounds__(512, 2) void lstm_persistent(
    const float* __restrict__ wv, const int* __restrict__ nw,
    const float* __restrict__ ic, const float* __restrict__ ih,
    const float* __restrict__ bias, const unsigned short* __restrict__ Wp,
    unsigned int* __restrict__ hg, float* __restrict__ out) {
  __shared__ __align__(16) unsigned short hlds[2][16 * 512];   // 32 KB (dbuf)
  __shared__ __align__(16) unsigned short xlds[2][16 * 512];   // 32 KB

  const int tid = threadIdx.x;
  const int wgid = blockIdx.x;
  const int mg = wgid & 7;   // row group
  const int hb = wgid >> 3;  // h-col block
  const int w = tid >> 6;    // wave 0..7
  const int lane = tid & 63;

  // per-lane cell (post-transpose): row er = q*4+gp, hcol kin = w*4+hc
  const int q = lane >> 4;
  const int gp = (lane >> 2) & 3;
  const int hc = lane & 3;
  const int er = (q << 2) + gp;
  const int kin = (w << 2) | hc;   // 0..31
  const int grow = (mg << 4) + er;
  const int gcol = (hb << 5) + kin;

  const int nwv = nw[grow];
  float c_reg = ic[grow * H_ + gcol];
  float h_reg = ih[grow * H_ + gcol];

  // W B-frags: kt 0..15 x-part (rows 0..511), 16..31 h-part
  uint4 wfrag[32];
  {
    const uint4* wp = (const uint4*)Wp + (size_t)((hb * 8 + w) * 32) * 64 + lane;
#pragma unroll
    for (int kt = 0; kt < 32; ++kt) wfrag[kt] = wp[kt * 64];
  }
  // bias for this lane's PRE-transpose accumulator column cb=(gp<<2)|hc
  const float bv = bias[(gp << 9) + (hb << 5) + kin];

  // 2 parity slots of tagged u64; slot s for group mg: 32 KB
  auto slot64 = [&](int s) { return (u64*)hg + (size_t)(s * 8 + mg) * 4096; };

  // this lane-pair's u64 index within the slot (even lanes store)
  // hslot (bf16 idx) = (hb<<9) + ((er | ((kin>>3)<<4))<<3) + (kin&7)
  const int hslot = (hb << 9) + ((er | ((kin >> 3) << 4)) << 3) + (kin & 7);
  const int ppair = hslot >> 1;

  auto publish_h = [&](u64* dst, unsigned int tag) {
    unsigned int hv = (unsigned int)f2bf(h_reg);
    unsigned int up = (unsigned int)__shfl_down((int)hv, 1);
    if ((lane & 1) == 0) {
      u64 vv = ((u64)tag << 32) | (u64)(hv | (up << 16));
      __hip_atomic_store(dst + ppair, vv, __ATOMIC_RELAXED,
                         __HIP_MEMORY_SCOPE_AGENT);
    }
  };

  // Poll-the-tag staging: wave w owns producers/k-tiles {2w, 2w+1}.
  // 8 u64 loads/lane/iter; success iff all 8 tags == want. Iteration-capped.
  auto wait_stage = [&](const u64* s, unsigned int want, unsigned short* dstlds) {
    u64 v0, v1, v2, v3, v4, v5, v6, v7;
    int it = 0;
    while (true) {
      v0 = __hip_atomic_load(s + (((2 * w + 0) << 8) + (0 << 6) + lane), __ATOMIC_RELAXED, __HIP_MEMORY_SCOPE_AGENT);
      v1 = __hip_atomic_load(s + (((2 * w + 0) << 8) + (1 << 6) + lane), __ATOMIC_RELAXED, __HIP_MEMORY_SCOPE_AGENT);
      v2 = __hip_atomic_load(s + (((2 * w + 0) << 8) + (2 << 6) + lane), __ATOMIC_RELAXED, __HIP_MEMORY_SCOPE_AGENT);
      v3 = __hip_atomic_load(s + (((2 * w + 0) << 8) + (3 << 6) + lane), __ATOMIC_RELAXED, __HIP_MEMORY_SCOPE_AGENT);
      v4 = __hip_atomic_load(s + (((2 * w + 1) << 8) + (0 << 6) + lane), __ATOMIC_RELAXED, __HIP_MEMORY_SCOPE_AGENT);
      v5 = __hip_atomic_load(s + (((2 * w + 1) << 8) + (1 << 6) + lane), __ATOMIC_RELAXED, __HIP_MEMORY_SCOPE_AGENT);
      v6 = __hip_atomic_load(s + (((2 * w + 1) << 8) + (2 << 6) + lane), __ATOMIC_RELAXED, __HIP_MEMORY_SCOPE_AGENT);
      v7 = __hip_atomic_load(s + (((2 * w + 1) << 8) + (3 << 6) + lane), __ATOMIC_RELAXED, __HIP_MEMORY_SCOPE_AGENT);
      bool ok = ((unsigned int)(v0 >> 32) == want) && ((unsigned int)(v1 >> 32) == want) &&
                ((unsigned int)(v2 >> 32) == want) && ((unsigned int)(v3 >> 32) == want) &&
                ((unsigned int)(v4 >> 32) == want) && ((unsigned int)(v5 >> 32) == want) &&
                ((unsigned int)(v6 >> 32) == want) && ((unsigned int)(v7 >> 32) == want);
      if (__all(ok)) break;
      if (++it > POLL_CAP) break;
      if (it > 4) __builtin_amdgcn_s_sleep(1);
    }
    unsigned int* d32 = (unsigned int*)dstlds;
    d32[((2 * w + 0) << 8) + (0 << 6) + lane] = (unsigned int)v0;
    d32[((2 * w + 0) << 8) + (1 << 6) + lane] = (unsigned int)v1;
    d32[((2 * w + 0) << 8) + (2 << 6) + lane] = (unsigned int)v2;
    d32[((2 * w + 0) << 8) + (3 << 6) + lane] = (unsigned int)v3;
    d32[((2 * w + 1) << 8) + (0 << 6) + lane] = (unsigned int)v4;
    d32[((2 * w + 1) << 8) + (1 << 6) + lane] = (unsigned int)v5;
    d32[((2 * w + 1) << 8) + (2 << 6) + lane] = (unsigned int)v6;
    d32[((2 * w + 1) << 8) + (3 << 6) + lane] = (unsigned int)v7;
  };

  // T14 split x staging: issue global->regs in phase B, commit at B end.
  float4 xr[4];
  auto xissue = [&](int tt) {
    if (tt >= T_) return;
#pragma unroll
    for (int s2 = 0; s2 < 2; ++s2) {
      int e = tid + (s2 << 9);
      int ktx = e >> 6;
      int le = e & 63;
      int r = le & 15;
      int d = (ktx << 5) + ((le >> 4) << 3);
      const float* src = wv + ((size_t)((mg << 4) + r) * T_ + tt) * D_ + d;
      xr[2 * s2] = *(const float4*)src;
      xr[2 * s2 + 1] = *(const float4*)(src + 4);
    }
  };
  auto xcommit = [&](int buf, int tt) {
    if (tt >= T_) return;
#pragma unroll
    for (int s2 = 0; s2 < 2; ++s2) {
      int e = tid + (s2 << 9);
      int ktx = e >> 6;
      int le = e & 63;
      float4 xa = xr[2 * s2], xb = xr[2 * s2 + 1];
      bf16x8 v;
      v[0] = (__bf16)xa.x; v[1] = (__bf16)xa.y; v[2] = (__bf16)xa.z; v[3] = (__bf16)xa.w;
      v[4] = (__bf16)xb.x; v[5] = (__bf16)xb.y; v[6] = (__bf16)xb.z; v[7] = (__bf16)xb.w;
      *(bf16x8*)&xlds[buf][(ktx << 9) + (le << 3)] = v;
    }
  };

  // x-part: two persistent accumulator chains (depth 8 each), consumed
  // directly by phase A's 4-chain reduction.
  f32x4 xA, xB;
  auto xpart = [&](int buf) {
    f32x4 A = {0.f, 0.f, 0.f, 0.f};
    f32x4 Bc = {0.f, 0.f, 0.f, 0.f};
#pragma unroll
    for (int kt = 0; kt < 8; ++kt) {
      bf16x8 a0 = *(const bf16x8*)&xlds[buf][(kt << 9) + (lane << 3)];
      bf16x8 a1 = *(const bf16x8*)&xlds[buf][((kt + 8) << 9) + (lane << 3)];
      A = __builtin_amdgcn_mfma_f32_16x16x32_bf16(
          a0, __builtin_bit_cast(bf16x8, wfrag[kt]), A, 0, 0, 0);
      Bc = __builtin_amdgcn_mfma_f32_16x16x32_bf16(
          a1, __builtin_bit_cast(bf16x8, wfrag[kt + 8]), Bc, 0, 0, 0);
    }
    xA = A;
    xB = Bc;
  };

  // ---- prologue: x[0]->buf0, x[1]->buf1, hlds[0] <- bf16(ih) directly ----
  xissue(0); xcommit(0, 0);
  xissue(1); xcommit(1, 1);
#pragma unroll
  for (int s2 = 0; s2 < 2; ++s2) {
    int e = tid + (s2 << 9);
    int ktx = e >> 6;
    int le = e & 63;
    int r = le & 15;
    int d = (ktx << 5) + ((le >> 4) << 3);
    const float* src = ih + (size_t)((mg << 4) + r) * H_ + d;
    float4 ha = *(const float4*)src;
    float4 hbv = *(const float4*)(src + 4);
    bf16x8 v;
    v[0] = (__bf16)ha.x; v[1] = (__bf16)ha.y; v[2] = (__bf16)ha.z; v[3] = (__bf16)ha.w;
    v[4] = (__bf16)hbv.x; v[5] = (__bf16)hbv.y; v[6] = (__bf16)hbv.z; v[7] = (__bf16)hbv.w;
    *(bf16x8*)&hlds[0][(ktx << 9) + (le << 3)] = v;
  }
  __syncthreads();
  xpart(0);

  for (int t = 0; t < T_; ++t) {
    const int par = t & 1;
    u64* hdst = slot64((t + 1) & 1);  // h[t+1]'s parity slot

    // ---- phase A (critical path): h-MFMAs (4 chains of 4) on hlds[par] ----
    const unsigned short* hsrc = hlds[par];
    f32x4 c0 = xA, c1 = xB;
    f32x4 c2 = {0.f, 0.f, 0.f, 0.f};
    f32x4 c3 = {0.f, 0.f, 0.f, 0.f};
#pragma unroll
    for (int i = 0; i < 4; ++i) {
      bf16x8 a0 = *(const bf16x8*)&hsrc[((4 * i) << 9) + (lane << 3)];
      bf16x8 a1 = *(const bf16x8*)&hsrc[((4 * i + 1) << 9) + (lane << 3)];
      bf16x8 a2 = *(const bf16x8*)&hsrc[((4 * i + 2) << 9) + (lane << 3)];
      bf16x8 a3 = *(const bf16x8*)&hsrc[((4 * i + 3) << 9) + (lane << 3)];
      c0 = __builtin_amdgcn_mfma_f32_16x16x32_bf16(
          a0, __builtin_bit_cast(bf16x8, wfrag[16 + 4 * i]), c0, 0, 0, 0);
      c1 = __builtin_amdgcn_mfma_f32_16x16x32_bf16(
          a1, __builtin_bit_cast(bf16x8, wfrag[17 + 4 * i]), c1, 0, 0, 0);
      c2 = __builtin_amdgcn_mfma_f32_16x16x32_bf16(
          a2, __builtin_bit_cast(bf16x8, wfrag[18 + 4 * i]), c2, 0, 0, 0);
      c3 = __builtin_amdgcn_mfma_f32_16x16x32_bf16(
          a3, __builtin_bit_cast(bf16x8, wfrag[19 + 4 * i]), c3, 0, 0, 0);
    }

    // ---- in-wave gates: z per reg, 4x4 (reg <-> lane[3:2]) transpose ----
    float z0 = (c0[0] + c1[0]) + (c2[0] + c3[0]) + bv;
    float z1 = (c0[1] + c1[1]) + (c2[1] + c3[1]) + bv;
    float z2 = (c0[2] + c1[2]) + (c2[2] + c3[2]) + bv;
    float z3 = (c0[3] + c1[3]) + (c2[3] + c3[3]) + bv;
    {
      bool b0 = gp & 1;  // lane bit 2
      float e;
      e = __shfl_xor(b0 ? z0 : z1, 4); if (b0) z0 = e; else z1 = e;
      e = __shfl_xor(b0 ? z2 : z3, 4); if (b0) z2 = e; else z3 = e;
      bool b1 = (gp >> 1) & 1;  // lane bit 3
      e = __shfl_xor(b1 ? z0 : z2, 8); if (b1) z0 = e; else z2 = e;
      e = __shfl_xor(b1 ? z1 : z3, 8); if (b1) z1 = e; else z3 = e;
    }
    // now lane holds z[row=er][gates i,j,f,o] = z0..z3 for hcol=gcol
    {
      float si = fast_sigmoid(z0);
      float tj = fast_tanh(z1);
      float sf = fast_sigmoid(z2 + 1.f);  // FORGET_BIAS
      float so = fast_sigmoid(z3);
      float nc = c_reg * sf + si * tj;
      float nh = fast_tanh(nc) * so;
      bool m = t < nwv;
      c_reg = m ? nc : c_reg;
      h_reg = m ? nh : h_reg;
      publish_h(hdst, (unsigned int)(t + 1));  // per-wave, right after MFMAs
      out[(size_t)t * (B_ * H_) + grow * H_ + gcol] = m ? nh : 0.f;
    }

    // ---- phase B (overlap): x-prefetch, x-part of t+1, stage h[t+1] ----
    if (t + 1 < T_) {
      xissue(t + 2);                                    // flies under B
      xpart(1 - par);                                   // x[t+1]
      wait_stage(hdst, (unsigned int)(t + 1), hlds[par ^ 1]);
      xcommit(par, t + 2);                              // regs -> xlds[par]
    }
    LBAR();  // single per-step barrier: hlds/xlds writes visible to phase A
  }

  size_t base = (size_t)T_ * (B_ * H_);
  out[base + grow * H_ + gcol] = c_reg;
  out[base + B_ * H_ + grow * H_ + gcol] = h_reg;
}

extern "C" void kernel_launch(void* const* d_in, const int* in_sizes, int n_in,
                              void* d_out, int out_size, void* d_ws, size_t ws_size,
                              hipStream_t stream) {
  const float* wv = (const float*)d_in[0];    // [B,T,D]
  const int* nw = (const int*)d_in[1];        // [B]
  const float* ic = (const float*)d_in[2];    // [B,H]
  const float* ih = (const float*)d_in[3];    // [B,H]
  const float* W = (const float*)d_in[4];     // [D+H, 4H]
  const float* bias = (const float*)d_in[5];  // [4H]
  float* out = (float*)d_out;

  char* ws = (char*)d_ws;
  unsigned short* Wp = (unsigned short*)ws;             // 4 MB packed W
  unsigned int* hg = (unsigned int*)(ws + (4u << 20));  // 512 KB: 2 slots x 8 groups x 32 KB

  init_ws_kernel<<<128, 1024, 0, stream>>>(hg);
  pack_w_kernel<<<(1 << 21) / 256, 256, 0, stream>>>(W, Wp);
  lstm_persistent<<<128, 512, 0, stream>>>(wv, nw, ic, ih, bias, Wp, hg, out);
}